// Round 8
// baseline (574.100 us; speedup 1.0000x reference)
//
#include <hip/hip_runtime.h>

typedef __attribute__((ext_vector_type(8))) short short8;
typedef __attribute__((ext_vector_type(4))) float floatx4;

#define MFMA16(a,b,c) __builtin_amdgcn_mfma_f32_16x16x32_bf16(a,b,c,0,0,0)

__device__ __forceinline__ unsigned short f2bf(float f){
  unsigned u = __float_as_uint(f);
  u += 0x7fffu + ((u >> 16) & 1u);
  return (unsigned short)(u >> 16);
}
// packed f32->bf16 (P-values only: any rounding-mode bias cancels in p/z)
__device__ __forceinline__ unsigned cvtpk(float lo, float hi){
  unsigned r;
  asm("v_cvt_pk_bf16_f32 %0, %1, %2" : "=v"(r) : "v"(lo), "v"(hi));
  return r;
}
__device__ __forceinline__ float sigm(float x){ return 1.f/(1.f+__expf(-x)); }
__device__ __forceinline__ float tanh_fast(float x){
  float e = __expf(2.f*x);
  return 1.f - 2.f/(e+1.f);
}

// WhB/WgA/WoA swizzled fragment layouts (K-groups G=8 for K=256, G=4 for K=128):
//  element (o, k):  off = ((o>>4)*G + (k>>5))*512 + (((k>>3)&3)*16 + (o&15))*8 + (k&7)
//  -> lane (quad*16+l16) of chunk (o16,kh) holds o = o16*16+l16, k = kh*32+quad*8+j.

// ---- fused prep: cell init + WgA/WoA swizzle + cwT transpose + adjacency bitmasks ----
__global__ __launch_bounds__(256) void prep_kernel(const float* __restrict__ actors,
    const float* __restrict__ Wg, const float* __restrict__ W, const float* __restrict__ cw,
    const int* __restrict__ adj, float* __restrict__ cell, unsigned short* __restrict__ WgA,
    unsigned short* __restrict__ WoA, float* __restrict__ cwT,
    unsigned long long* __restrict__ bm){
  int bid = blockIdx.x;
  if (bid < 1024){
    int idx = bid*256 + threadIdx.x;
    int n = idx >> 7, c = idx & 127;
    cell[idx] = actors[(size_t)n*2560 + c];
  } else if (bid < 1536){
    int e = (bid-1024)*256 + threadIdx.x;            // 131072
    int g = e >> 15, o = (e >> 8) & 127, k = e & 255;
    unsigned short v = f2bf(Wg[(size_t)g*32768 + k*128 + o]);
    int off = ((o>>4)*8 + (k>>5))*512 + (((k>>3)&3)*16 + (o&15))*8 + (k&7);
    WgA[(size_t)g*32768 + off] = v;
  } else if (bid < 1728){
    int e = (bid-1536)*256 + threadIdx.x;            // 49152
    int l = e >> 14, rr = e & 16383, k = rr >> 7, o = rr & 127;
    cwT[(size_t)l*32768 + k*256 + o]       = cw[(size_t)l*32768 + o*256 + k*2];
    cwT[(size_t)l*32768 + k*256 + 128 + o] = cw[(size_t)l*32768 + o*256 + k*2 + 1];
  } else if (bid < 1792){
    int e = (bid-1728)*256 + threadIdx.x;            // 16384: W[k][o] -> WoA bf16 swizzled
    int k = e >> 7, o = e & 127;
    unsigned short v = f2bf(W[(size_t)k*128 + o]);
    int off = ((o>>4)*4 + (k>>5))*512 + (((k>>3)&3)*16 + (o&15))*8 + (k&7);
    WoA[off] = v;
  } else {
    const int E[4] = {0,4,9,14};
    int mb = bid - 1792;                             // 2048 blocks
    int t = mb & 3, nblk = mb >> 2;
    int wv = threadIdx.x >> 6, lane = threadIdx.x & 63;
    int n = nblk*4 + wv;
    const int* row = adj + (size_t)n*40960 + (size_t)E[t]*2048;
    unsigned long long* outp = bm + ((size_t)t*2048 + n)*32;
    for (int it=0; it<32; ++it){
      unsigned long long bal = __ballot(row[it*64 + lane] > 0);
      if (lane == 0) outp[it] = bal;
    }
  }
}

// ---- fused: LSTM gate + MFMA y-outproj + 4-gate Wh GEMM ----
// grid 256 = (tile 0..127) x (o-half); 512 threads = 8 waves (1 block/CU, 2/SIMD).
// spart layout: [(ohalf*2+which)*4+g][2048], which: 0=src 1=dst.
__global__ __launch_bounds__(512,2) void gatewh_kernel(const float* __restrict__ actors,
    const float* __restrict__ gbuf, float* __restrict__ cell, const float* __restrict__ h0,
    const float* __restrict__ bvec, const unsigned short* __restrict__ WgA,
    const unsigned short* __restrict__ WoA, const float* __restrict__ ag,
    float* __restrict__ y, unsigned short* __restrict__ WhB,
    float* __restrict__ spart, int xoff, int t){
  __shared__ float hl[16][132];
  __shared__ __align__(16) unsigned short ginb[16*264];
  __shared__ float sredS[4][4][16], sredD[4][4][16];
  int bx = blockIdx.x;
  int tile = bx >> 1, ohalf = bx & 1;
  int n0 = tile*16, tid = threadIdx.x;
  int row = tid>>5, q = tid&31;
  // Phase A: hidden (+cell from previous gates); 4 cols/thread
  {
    int o0 = q*4;
    if (t == 0){
      *(float4*)&hl[row][o0] = *(const float4*)(h0 + o0);
    } else {
      size_t idx = (size_t)(n0+row)*128 + o0;
      float4 ga = *(const float4*)(gbuf+idx);
      float4 gb = *(const float4*)(gbuf+262144+idx);
      float4 gc = *(const float4*)(gbuf+524288+idx);
      float4 gd = *(const float4*)(gbuf+786432+idx);
      float4 cv = *(const float4*)(cell+idx);
      float fg[4]={ga.x,ga.y,ga.z,ga.w}, ig[4]={gb.x,gb.y,gb.z,gb.w};
      float ic[4]={gc.x,gc.y,gc.z,gc.w}, og[4]={gd.x,gd.y,gd.z,gd.w};
      float cc[4]={cv.x,cv.y,cv.z,cv.w};
      float clv[4];
      #pragma unroll
      for (int j=0;j<4;++j){
        clv[j] = cc[j]*sigm(fg[j]) + sigm(ig[j])*tanh_fast(ic[j]);
        hl[row][o0+j] = tanh_fast(clv[j])*sigm(og[j]);
      }
      if (ohalf == 0)
        *(float4*)(cell+idx) = (float4){clv[0],clv[1],clv[2],clv[3]};
    }
  }
  __syncthreads();
  // Phase B: gin bf16 = [X | hidden]
  if (q < 16){
    const float* ap = actors + (size_t)(n0+row)*2560 + xoff + q*8;
    float4 a = *(const float4*)ap, bb = *(const float4*)(ap+4);
    unsigned short tmp[8] = {f2bf(a.x),f2bf(a.y),f2bf(a.z),f2bf(a.w),
                             f2bf(bb.x),f2bf(bb.y),f2bf(bb.z),f2bf(bb.w)};
    *(uint4*)&ginb[row*264 + q*8] = *(const uint4*)tmp;
  } else {
    int c0 = (q-16)*8;
    unsigned short tmp[8];
    #pragma unroll
    for (int j=0;j<8;++j) tmp[j] = f2bf(hl[row][c0+j]);
    *(uint4*)&ginb[row*264 + 128 + c0] = *(const uint4*)tmp;
  }
  __syncthreads();
  // Phase C: 8 waves x 2 (g,o16) chunks; waves 0-3 also do the y outproj MFMA
  int w = tid>>6, lane = tid&63, quad = lane>>4, l16 = lane&15;
  int m32 = tile>>1, min32 = (tile&1)*16 + l16;
  int qp = min32>>3, jp = min32&7;
  if (t >= 1 && w < 4){
    int o16 = ohalf*4 + w;
    floatx4 acc = {0.f,0.f,0.f,0.f};
    #pragma unroll
    for (int kh=0; kh<4; ++kh){
      short8 bfr = *(const short8*)&ginb[l16*264 + 128 + kh*32 + quad*8];  // hidden bf16
      short8 a0 = *(const short8*)(WoA + (size_t)((o16*4 + kh)*64 + lane)*8);
      acc = MFMA16(a0, bfr, acc);
    }
    int oc = o16*16 + quad*4;
    float4 bb = *(const float4*)(bvec + oc);
    float4 res = {sigm(acc[0]+bb.x), sigm(acc[1]+bb.y),
                  sigm(acc[2]+bb.z), sigm(acc[3]+bb.w)};
    *(float4*)(y + (size_t)(t-1)*262144 + (size_t)(n0+l16)*128 + oc) = res;
  }
  #pragma unroll
  for (int ci=0; ci<2; ++ci){
    int cidx = w*2 + ci;                 // 0..15
    int g = cidx>>2, o16q = cidx&3, o16 = ohalf*4 + o16q;
    floatx4 acc = {0.f,0.f,0.f,0.f};
    const unsigned short* wa = WgA + (size_t)g*32768;
    #pragma unroll
    for (int kh=0; kh<8; ++kh){
      short8 bfr = *(const short8*)&ginb[l16*264 + kh*32 + quad*8];
      short8 a0 = *(const short8*)(wa + (size_t)((o16*8 + kh)*64 + lane)*8);
      acc = MFMA16(a0, bfr, acc);
    }
    float ps = 0.f, pd = 0.f;
    unsigned short* wb = WhB + (size_t)(g*8 + o16)*32768 + m32*512 + qp*128 + jp;
    const float* agp = ag + g*256;
    #pragma unroll
    for (int r=0;r<4;++r){
      int o = o16*16 + quad*4 + r;
      float v = acc[r];
      ps += v*agp[o]; pd += v*agp[128+o];
      wb[(quad*4+r)*8] = f2bf(v);
    }
    ps += __shfl_down(ps,32); ps += __shfl_down(ps,16);
    pd += __shfl_down(pd,32); pd += __shfl_down(pd,16);
    if (lane < 16){ sredS[g][o16q][l16] = ps; sredD[g][o16q][l16] = pd; }
  }
  __syncthreads();
  if (tid < 128){
    int g = tid>>5, which = (tid>>4)&1, n = tid&15;
    float s;
    if (which) s = sredD[g][0][n]+sredD[g][1][n]+sredD[g][2][n]+sredD[g][3][n];
    else       s = sredS[g][0][n]+sredS[g][1][n]+sredS[g][2][n]+sredS[g][3][n];
    spart[(size_t)((ohalf*2 + which)*4 + g)*2048 + n0 + n] = s;
  }
}

// ---- fused masked-softmax + PV: 64 rows x o-half per block ----
// grid 256: g = bid&3 (XCD-affine), rowblk = bid>>3, ohalf = (bid>>2)&1.
// Each block stages only 4 o16-planes (256 KB) -> per-XCD L2 traffic halved vs
// 32-row/full-o. 8 m-eighth waves; per wave 4 row-group A-chains (quad-A).
// Counted s_waitcnt vmcnt(4): 4 gll/slab, double-buffered, never 0 mid-loop.
__global__ __launch_bounds__(512,2) void attn_kernel(const unsigned char* __restrict__ bmb,
    const unsigned short* __restrict__ WhB, const float* __restrict__ spart,
    float* __restrict__ gout, int t){
  __shared__ __align__(16) unsigned char smem[67584];  // stage[2][8][4096] -> obuf[4][64][66]
  __shared__ float ssum[2048];
  __shared__ float zpart[8][64];
  int bid = blockIdx.x;
  int g = bid & 3, rb = bid >> 2;
  int rowblk = rb >> 1, ohalf = rb & 1;
  int n0 = rowblk*64;
  int tid = threadIdx.x;
  int w = tid>>6, lane = tid&63, quad = lane>>4, l16 = lane&15;
  const float* sS0 = spart + (size_t)(0 + g)*2048;
  const float* sD0 = spart + (size_t)(4 + g)*2048;
  const float* sS1 = spart + (size_t)(8 + g)*2048;
  const float* sD1 = spart + (size_t)(12 + g)*2048;
  const unsigned short* wb0 = WhB + (size_t)(g*8 + ohalf*4)*32768;  // 4 o16q planes, +32768 each

  // mask strips first (older in vmcnt FIFO than any stage gll)
  unsigned mwd[4][8];
  #pragma unroll
  for (int rg=0; rg<4; ++rg){
    const unsigned char* mr = bmb + ((size_t)t*2048 + n0 + rg*16 + l16)*256 + w*32;
    uint4 a = *(const uint4*)mr, b = *(const uint4*)(mr+16);
    mwd[rg][0]=a.x; mwd[rg][1]=a.y; mwd[rg][2]=a.z; mwd[rg][3]=a.w;
    mwd[rg][4]=b.x; mwd[rg][5]=b.y; mwd[rg][6]=b.z; mwd[rg][7]=b.w;
  }
  float srcv[4];
  #pragma unroll
  for (int rg=0; rg<4; ++rg)
    srcv[rg] = sS0[n0 + rg*16 + l16] + sS1[n0 + rg*16 + l16];

  // stage group 0 (4 async 1KB chunks)
  {
    unsigned char* lp = smem + (size_t)w*4096;
    const unsigned short* gs = wb0 + (size_t)(w*8)*512 + lane*8;
    #pragma unroll
    for (int oq=0; oq<4; ++oq)
      __builtin_amdgcn_global_load_lds((const void*)(gs + (size_t)oq*32768),
                                       (void*)(lp + oq*1024), 16, 0, 0);
  }
  // ssum = sD0+sD1 (self-wave region: tid*4 in [w*256, w*256+256))
  {
    float4 d0 = *(const float4*)(sD0 + tid*4);
    float4 d1 = *(const float4*)(sD1 + tid*4);
    *(float4*)&ssum[tid*4] = (float4){d0.x+d1.x, d0.y+d1.y, d0.z+d1.z, d0.w+d1.w};
  }
  float z[4] = {0.f,0.f,0.f,0.f};
  floatx4 acc[4][4];
  #pragma unroll
  for (int rg=0;rg<4;++rg)
    #pragma unroll
    for (int oq=0;oq<4;++oq) acc[rg][oq] = (floatx4){0.f,0.f,0.f,0.f};

  #pragma unroll
  for (int c=0; c<8; ++c){
    const int cur = c & 1;
    if (c < 7){
      unsigned char* lp = smem + (size_t)(((c+1)&1)*8 + w)*4096;
      const unsigned short* gs = wb0 + (size_t)(w*8 + c + 1)*512 + lane*8;
      #pragma unroll
      for (int oq=0; oq<4; ++oq)
        __builtin_amdgcn_global_load_lds((const void*)(gs + (size_t)oq*32768),
                                         (void*)(lp + oq*1024), 16, 0, 0);
      asm volatile("s_waitcnt vmcnt(4)" ::: "memory");   // group c landed (FIFO)
    } else {
      asm volatile("s_waitcnt vmcnt(0)" ::: "memory");
    }
    __builtin_amdgcn_sched_barrier(0);
    int mk = w*256 + c*32 + quad*8;
    float4 sa = *(const float4*)&ssum[mk];
    float4 sb = *(const float4*)&ssum[mk+4];
    float sv[8] = {sa.x,sa.y,sa.z,sa.w, sb.x,sb.y,sb.z,sb.w};
    short8 bfr[4];
    const unsigned char* sbase = smem + (size_t)(cur*8 + w)*4096 + lane*16;
    #pragma unroll
    for (int oq=0; oq<4; ++oq) bfr[oq] = *(const short8*)(sbase + oq*1024);
    #pragma unroll
    for (int rg=0; rg<4; ++rg){
      unsigned mb = (mwd[rg][c] >> (quad*8)) & 0xffu;
      float p[8];
      #pragma unroll
      for (int j=0;j<8;++j){
        float s = srcv[rg] + sv[j];
        s = fmaxf(s, 0.2f*s);                      // leaky_relu (bit-exact)
        p[j] = ((mb >> j) & 1u) ? __expf(s) : 0.f;
        z[rg] += p[j];
      }
      union { short8 v; unsigned u[4]; } A;
      #pragma unroll
      for (int j2=0;j2<4;++j2) A.u[j2] = cvtpk(p[2*j2], p[2*j2+1]);
      #pragma unroll
      for (int oq=0; oq<4; ++oq)
        acc[rg][oq] = MFMA16(A.v, bfr[oq], acc[rg][oq]);
    }
  }
  #pragma unroll
  for (int rg=0; rg<4; ++rg){
    z[rg] += __shfl_down(z[rg],32);
    z[rg] += __shfl_down(z[rg],16);
  }
  if (lane < 16){
    #pragma unroll
    for (int rg=0; rg<4; ++rg) zpart[w][rg*16+l16] = z[rg];
  }
  __syncthreads();                     // stage dead -> obuf overlay safe
  float (*obuf)[64][66] = (float (*)[64][66])smem;   // 67.6 KB
  if (w < 4){
    #pragma unroll
    for (int rg=0; rg<4; ++rg)
      #pragma unroll
      for (int oq=0; oq<4; ++oq)
        #pragma unroll
        for (int r=0; r<4; ++r)
          obuf[w][rg*16+quad*4+r][oq*16+l16] = acc[rg][oq][r];
  }
  __syncthreads();
  if (w >= 4){
    #pragma unroll
    for (int rg=0; rg<4; ++rg)
      #pragma unroll
      for (int oq=0; oq<4; ++oq)
        #pragma unroll
        for (int r=0; r<4; ++r)
          obuf[w-4][rg*16+quad*4+r][oq*16+l16] += acc[rg][oq][r];
  }
  __syncthreads();
  { // normalize + elu + store: 64 rows x 64 cols / 512 threads = 8/thread
    int row = tid>>3, c0 = (tid&7)*8;
    float zz = zpart[0][row]+zpart[1][row]+zpart[2][row]+zpart[3][row]
             + zpart[4][row]+zpart[5][row]+zpart[6][row]+zpart[7][row];
    float inv = 1.f / zz;
    float* go = gout + (size_t)g*262144 + (size_t)(n0+row)*128 + ohalf*64 + c0;
    #pragma unroll
    for (int j=0;j<8;++j){
      float v = (obuf[0][row][c0+j] + obuf[1][row][c0+j]
               + obuf[2][row][c0+j] + obuf[3][row][c0+j]) * inv;
      go[j] = v > 0.f ? v : __expf(v) - 1.f;       // elu
    }
  }
}

// ---- final gate + y3 + all 3 temporal conv layers; 4 rows/block, 512 blocks ----
__global__ __launch_bounds__(256) void convgate_kernel(const float* __restrict__ gbuf,
    const float* __restrict__ cell, const float* __restrict__ W, const float* __restrict__ bvec,
    const float* __restrict__ y, const float* __restrict__ cwT, const float* __restrict__ cb,
    float* __restrict__ out){
  __shared__ float hl[4][128];
  __shared__ float ylds[4][128][4];
  int tid = threadIdx.x;
  int r = tid >> 6, oc = (tid & 63)*2;
  int n = blockIdx.x*4 + r;
  size_t idx = (size_t)n*128 + oc;
  { // gate_3
    float2 g0 = *(const float2*)(gbuf+idx),        g1 = *(const float2*)(gbuf+262144+idx);
    float2 g2 = *(const float2*)(gbuf+524288+idx), g3 = *(const float2*)(gbuf+786432+idx);
    float2 cv = *(const float2*)(cell+idx);
    float fg[2]={g0.x,g0.y}, ig[2]={g1.x,g1.y}, ic[2]={g2.x,g2.y}, og[2]={g3.x,g3.y};
    float cc[2]={cv.x,cv.y};
    #pragma unroll
    for (int j=0;j<2;++j){
      float cl = cc[j]*sigm(fg[j]) + sigm(ig[j])*tanh_fast(ic[j]);
      hl[r][oc+j] = tanh_fast(cl)*sigm(og[j]);
    }
  }
  {
    float2 y0 = *(const float2*)(y+idx), y1 = *(const float2*)(y+262144+idx),
           y2 = *(const float2*)(y+524288+idx);
    float a0[2]={y0.x,y0.y}, a1[2]={y1.x,y1.y}, a2[2]={y2.x,y2.y};
    #pragma unroll
    for (int j=0;j<2;++j){
      ylds[r][oc+j][0]=a0[j]; ylds[r][oc+j][1]=a1[j]; ylds[r][oc+j][2]=a2[j];
    }
  }
  __syncthreads();
  { // y3 outproj
    float2 bb = *(const float2*)(bvec+oc);
    float acc[2] = {bb.x, bb.y};
    const float* hr = hl[r];
    for (int k=0;k<128;++k){
      float hv = hr[k];
      float2 wv = *(const float2*)(W + (size_t)k*128 + oc);
      acc[0]+=hv*wv.x; acc[1]+=hv*wv.y;
    }
    #pragma unroll
    for (int j=0;j<2;++j) ylds[r][oc+j][3] = sigm(acc[j]);
  }
  __syncthreads();
  { // layer 0: 4 -> 3
    float a0[2]={0,0}, a1[2]={0,0}, a2[2]={0,0};
    for (int k=0;k<128;++k){
      float2 w0 = *(const float2*)(cwT + k*256 + oc);
      float2 w1 = *(const float2*)(cwT + k*256 + 128 + oc);
      float4 yv = *(const float4*)&ylds[r][k][0];
      float wa[2]={w0.x,w0.y}, wb2[2]={w1.x,w1.y};
      #pragma unroll
      for (int j=0;j<2;++j){
        a0[j] += yv.x*wa[j] + yv.y*wb2[j];
        a1[j] += yv.y*wa[j] + yv.z*wb2[j];
        a2[j] += yv.z*wa[j] + yv.w*wb2[j];
      }
    }
    float2 bb = *(const float2*)(cb+oc);
    float bbv[2]={bb.x,bb.y};
    __syncthreads();
    #pragma unroll
    for (int j=0;j<2;++j){
      ylds[r][oc+j][0]=a0[j]+bbv[j]; ylds[r][oc+j][1]=a1[j]+bbv[j]; ylds[r][oc+j][2]=a2[j]+bbv[j];
    }
    __syncthreads();
  }
  { // layer 1: 3 -> 2
    float a0[2]={0,0}, a1[2]={0,0};
    for (int k=0;k<128;++k){
      float2 w0 = *(const float2*)(cwT + 32768 + k*256 + oc);
      float2 w1 = *(const float2*)(cwT + 32768 + k*256 + 128 + oc);
      float4 yv = *(const float4*)&ylds[r][k][0];
      float wa[2]={w0.x,w0.y}, wb2[2]={w1.x,w1.y};
      #pragma unroll
      for (int j=0;j<2;++j){
        a0[j] += yv.x*wa[j] + yv.y*wb2[j];
        a1[j] += yv.y*wa[j] + yv.z*wb2[j];
      }
    }
    float2 bb = *(const float2*)(cb+128+oc);
    float bbv[2]={bb.x,bb.y};
    __syncthreads();
    #pragma unroll
    for (int j=0;j<2;++j){
      ylds[r][oc+j][0]=a0[j]+bbv[j]; ylds[r][oc+j][1]=a1[j]+bbv[j];
    }
    __syncthreads();
  }
  { // layer 2: 2 -> 1
    float a0[2]={0,0};
    for (int k=0;k<128;++k){
      float2 w0 = *(const float2*)(cwT + 65536 + k*256 + oc);
      float2 w1 = *(const float2*)(cwT + 65536 + k*256 + 128 + oc);
      float4 yv = *(const float4*)&ylds[r][k][0];
      a0[0] += yv.x*w0.x + yv.y*w1.x;
      a0[1] += yv.x*w0.y + yv.y*w1.y;
    }
    float2 bb = *(const float2*)(cb+256+oc);
    float2 res = {a0[0]+bb.x, a0[1]+bb.y};
    *(float2*)(out+idx) = res;
  }
}

extern "C" void kernel_launch(void* const* d_in, const int* in_sizes, int n_in,
                              void* d_out, int out_size, void* d_ws, size_t ws_size,
                              hipStream_t stream) {
  const float* actors = (const float*)d_in[0];
  const int*   adj    = (const int*)d_in[1];
  const float* Wg     = (const float*)d_in[2];
  const float* ag     = (const float*)d_in[3];
  const float* W      = (const float*)d_in[4];
  const float* b      = (const float*)d_in[5];
  const float* h0     = (const float*)d_in[6];
  const float* cw     = (const float*)d_in[7];
  const float* cb     = (const float*)d_in[8];
  float* out = (float*)d_out;

  char* ws = (char*)d_ws;
  unsigned long long* bm = (unsigned long long*)ws;                  // 2 MB
  float* cell          = (float*)(ws + (size_t)(2u<<20));            // 1 MB
  unsigned short* WgA  = (unsigned short*)(ws + (size_t)(3u<<20));   // 256 KB bf16 swizzled
  float* cwT           = (float*)(ws + (size_t)3407872);             // 384 KB
  unsigned short* WoA  = (unsigned short*)(ws + (size_t)3801088);    // 32 KB bf16 swizzled
  float* spart         = (float*)(ws + (size_t)3932160);             // 128 KB [16][2048]
  unsigned short* WhB  = (unsigned short*)(ws + (size_t)(4u<<20));   // 2 MB bf16 swizzled
  float* gbuf          = (float*)(ws + (size_t)(7u<<20));            // 4 MB [g][n][o]
  float* yplanes       = (float*)(ws + (size_t)(11u<<20));           // 3 MB [t][n][o]

  const int XI[4] = {4, 9, 14, 19};

  prep_kernel<<<3840, 256, 0, stream>>>(actors, Wg, W, cw, adj, cell, WgA, WoA, cwT, bm);
  for (int t=0; t<4; ++t){
    gatewh_kernel<<<256, 512, 0, stream>>>(actors, gbuf, cell, h0, b, WgA, WoA, ag,
                                           yplanes, WhB, spart, XI[t]*128, t);
    attn_kernel<<<256, 512, 0, stream>>>((const unsigned char*)bm, WhB,
                                         spart, gbuf, t);
  }
  convgate_kernel<<<512, 256, 0, stream>>>(gbuf, cell, W, b, yplanes, cwT, cb, out);
}

// Round 9
// 556.293 us; speedup vs baseline: 1.0320x; 1.0320x over previous
//
#include <hip/hip_runtime.h>

typedef __attribute__((ext_vector_type(8))) short short8;
typedef __attribute__((ext_vector_type(4))) float floatx4;

#define MFMA16(a,b,c) __builtin_amdgcn_mfma_f32_16x16x32_bf16(a,b,c,0,0,0)

__device__ __forceinline__ unsigned short f2bf(float f){
  unsigned u = __float_as_uint(f);
  u += 0x7fffu + ((u >> 16) & 1u);
  return (unsigned short)(u >> 16);
}
// packed f32->bf16 (P-values only; verified safe in round 8: absmax unchanged)
__device__ __forceinline__ unsigned cvtpk(float lo, float hi){
  unsigned r;
  asm("v_cvt_pk_bf16_f32 %0, %1, %2" : "=v"(r) : "v"(lo), "v"(hi));
  return r;
}
__device__ __forceinline__ float sigm(float x){ return 1.f/(1.f+__expf(-x)); }
__device__ __forceinline__ float tanh_fast(float x){
  float e = __expf(2.f*x);
  return 1.f - 2.f/(e+1.f);
}

// WhB/WgA/WoA swizzled fragment layouts (K-groups G=8 for K=256, G=4 for K=128):
//  element (o, k):  off = ((o>>4)*G + (k>>5))*512 + (((k>>3)&3)*16 + (o&15))*8 + (k&7)
//  -> lane (quad*16+l16) of chunk (o16,kh) holds o = o16*16+l16, k = kh*32+quad*8+j.

// ---- fused prep: cell init + WgA/WoA swizzle + cwT transpose + adjacency bitmasks ----
__global__ __launch_bounds__(256) void prep_kernel(const float* __restrict__ actors,
    const float* __restrict__ Wg, const float* __restrict__ W, const float* __restrict__ cw,
    const int* __restrict__ adj, float* __restrict__ cell, unsigned short* __restrict__ WgA,
    unsigned short* __restrict__ WoA, float* __restrict__ cwT,
    unsigned long long* __restrict__ bm){
  int bid = blockIdx.x;
  if (bid < 1024){
    int idx = bid*256 + threadIdx.x;
    int n = idx >> 7, c = idx & 127;
    cell[idx] = actors[(size_t)n*2560 + c];
  } else if (bid < 1536){
    int e = (bid-1024)*256 + threadIdx.x;            // 131072
    int g = e >> 15, o = (e >> 8) & 127, k = e & 255;
    unsigned short v = f2bf(Wg[(size_t)g*32768 + k*128 + o]);
    int off = ((o>>4)*8 + (k>>5))*512 + (((k>>3)&3)*16 + (o&15))*8 + (k&7);
    WgA[(size_t)g*32768 + off] = v;
  } else if (bid < 1728){
    int e = (bid-1536)*256 + threadIdx.x;            // 49152
    int l = e >> 14, rr = e & 16383, k = rr >> 7, o = rr & 127;
    cwT[(size_t)l*32768 + k*256 + o]       = cw[(size_t)l*32768 + o*256 + k*2];
    cwT[(size_t)l*32768 + k*256 + 128 + o] = cw[(size_t)l*32768 + o*256 + k*2 + 1];
  } else if (bid < 1792){
    int e = (bid-1728)*256 + threadIdx.x;            // 16384: W[k][o] -> WoA bf16 swizzled
    int k = e >> 7, o = e & 127;
    unsigned short v = f2bf(W[(size_t)k*128 + o]);
    int off = ((o>>4)*4 + (k>>5))*512 + (((k>>3)&3)*16 + (o&15))*8 + (k&7);
    WoA[off] = v;
  } else {
    const int E[4] = {0,4,9,14};
    int mb = bid - 1792;                             // 2048 blocks
    int t = mb & 3, nblk = mb >> 2;
    int wv = threadIdx.x >> 6, lane = threadIdx.x & 63;
    int n = nblk*4 + wv;
    const int* row = adj + (size_t)n*40960 + (size_t)E[t]*2048;
    unsigned long long* outp = bm + ((size_t)t*2048 + n)*32;
    for (int it=0; it<32; ++it){
      unsigned long long bal = __ballot(row[it*64 + lane] > 0);
      if (lane == 0) outp[it] = bal;
    }
  }
}

// ---- fused: LSTM gate + MFMA y-outproj + 4-gate Wh GEMM ----
// grid 256 = (tile 0..127) x (o-half); 512 threads = 8 waves (1 block/CU, 2/SIMD).
// spart layout: [(ohalf*2+which)*4+g][2048], which: 0=src 1=dst.
__global__ __launch_bounds__(512,2) void gatewh_kernel(const float* __restrict__ actors,
    const float* __restrict__ gbuf, float* __restrict__ cell, const float* __restrict__ h0,
    const float* __restrict__ bvec, const unsigned short* __restrict__ WgA,
    const unsigned short* __restrict__ WoA, const float* __restrict__ ag,
    float* __restrict__ y, unsigned short* __restrict__ WhB,
    float* __restrict__ spart, int xoff, int t){
  __shared__ float hl[16][132];
  __shared__ __align__(16) unsigned short ginb[16*264];
  __shared__ float sredS[4][4][16], sredD[4][4][16];
  int bx = blockIdx.x;
  int tile = bx >> 1, ohalf = bx & 1;
  int n0 = tile*16, tid = threadIdx.x;
  int row = tid>>5, q = tid&31;
  // Phase A: hidden (+cell from previous gates); 4 cols/thread
  {
    int o0 = q*4;
    if (t == 0){
      *(float4*)&hl[row][o0] = *(const float4*)(h0 + o0);
    } else {
      size_t idx = (size_t)(n0+row)*128 + o0;
      float4 ga = *(const float4*)(gbuf+idx);
      float4 gb = *(const float4*)(gbuf+262144+idx);
      float4 gc = *(const float4*)(gbuf+524288+idx);
      float4 gd = *(const float4*)(gbuf+786432+idx);
      float4 cv = *(const float4*)(cell+idx);
      float fg[4]={ga.x,ga.y,ga.z,ga.w}, ig[4]={gb.x,gb.y,gb.z,gb.w};
      float ic[4]={gc.x,gc.y,gc.z,gc.w}, og[4]={gd.x,gd.y,gd.z,gd.w};
      float cc[4]={cv.x,cv.y,cv.z,cv.w};
      float clv[4];
      #pragma unroll
      for (int j=0;j<4;++j){
        clv[j] = cc[j]*sigm(fg[j]) + sigm(ig[j])*tanh_fast(ic[j]);
        hl[row][o0+j] = tanh_fast(clv[j])*sigm(og[j]);
      }
      if (ohalf == 0)
        *(float4*)(cell+idx) = (float4){clv[0],clv[1],clv[2],clv[3]};
    }
  }
  __syncthreads();
  // Phase B: gin bf16 = [X | hidden]
  if (q < 16){
    const float* ap = actors + (size_t)(n0+row)*2560 + xoff + q*8;
    float4 a = *(const float4*)ap, bb = *(const float4*)(ap+4);
    unsigned short tmp[8] = {f2bf(a.x),f2bf(a.y),f2bf(a.z),f2bf(a.w),
                             f2bf(bb.x),f2bf(bb.y),f2bf(bb.z),f2bf(bb.w)};
    *(uint4*)&ginb[row*264 + q*8] = *(const uint4*)tmp;
  } else {
    int c0 = (q-16)*8;
    unsigned short tmp[8];
    #pragma unroll
    for (int j=0;j<8;++j) tmp[j] = f2bf(hl[row][c0+j]);
    *(uint4*)&ginb[row*264 + 128 + c0] = *(const uint4*)tmp;
  }
  __syncthreads();
  // Phase C: 8 waves x 2 (g,o16) chunks; waves 0-3 also do the y outproj MFMA
  int w = tid>>6, lane = tid&63, quad = lane>>4, l16 = lane&15;
  int m32 = tile>>1, min32 = (tile&1)*16 + l16;
  int qp = min32>>3, jp = min32&7;
  if (t >= 1 && w < 4){
    int o16 = ohalf*4 + w;
    floatx4 acc = {0.f,0.f,0.f,0.f};
    #pragma unroll
    for (int kh=0; kh<4; ++kh){
      short8 bfr = *(const short8*)&ginb[l16*264 + 128 + kh*32 + quad*8];  // hidden bf16
      short8 a0 = *(const short8*)(WoA + (size_t)((o16*4 + kh)*64 + lane)*8);
      acc = MFMA16(a0, bfr, acc);
    }
    int oc = o16*16 + quad*4;
    float4 bb = *(const float4*)(bvec + oc);
    float4 res = {sigm(acc[0]+bb.x), sigm(acc[1]+bb.y),
                  sigm(acc[2]+bb.z), sigm(acc[3]+bb.w)};
    *(float4*)(y + (size_t)(t-1)*262144 + (size_t)(n0+l16)*128 + oc) = res;
  }
  #pragma unroll
  for (int ci=0; ci<2; ++ci){
    int cidx = w*2 + ci;                 // 0..15
    int g = cidx>>2, o16q = cidx&3, o16 = ohalf*4 + o16q;
    floatx4 acc = {0.f,0.f,0.f,0.f};
    const unsigned short* wa = WgA + (size_t)g*32768;
    #pragma unroll
    for (int kh=0; kh<8; ++kh){
      short8 bfr = *(const short8*)&ginb[l16*264 + kh*32 + quad*8];
      short8 a0 = *(const short8*)(wa + (size_t)((o16*8 + kh)*64 + lane)*8);
      acc = MFMA16(a0, bfr, acc);
    }
    float ps = 0.f, pd = 0.f;
    unsigned short* wb = WhB + (size_t)(g*8 + o16)*32768 + m32*512 + qp*128 + jp;
    const float* agp = ag + g*256;
    #pragma unroll
    for (int r=0;r<4;++r){
      int o = o16*16 + quad*4 + r;
      float v = acc[r];
      ps += v*agp[o]; pd += v*agp[128+o];
      wb[(quad*4+r)*8] = f2bf(v);
    }
    ps += __shfl_down(ps,32); ps += __shfl_down(ps,16);
    pd += __shfl_down(pd,32); pd += __shfl_down(pd,16);
    if (lane < 16){ sredS[g][o16q][l16] = ps; sredD[g][o16q][l16] = pd; }
  }
  __syncthreads();
  if (tid < 128){
    int g = tid>>5, which = (tid>>4)&1, n = tid&15;
    float s;
    if (which) s = sredD[g][0][n]+sredD[g][1][n]+sredD[g][2][n]+sredD[g][3][n];
    else       s = sredS[g][0][n]+sredS[g][1][n]+sredS[g][2][n]+sredS[g][3][n];
    spart[(size_t)((ohalf*2 + which)*4 + g)*2048 + n0 + n] = s;
  }
}

// ---- fused masked-softmax + PV: 512 thr = 8 m-waves, 32 rows (dual A-chain) ----
// 1D grid 256: g = bid&3, n0 = (bid>>2)*32 (XCD-affine: one WhB g-plane per XCD L2).
// B-fragments staged per-wave via async global_load_lds (width 16), double-buffered
// at c granularity with counted s_waitcnt vmcnt(8) (never 0 mid-loop). No cross-wave
// sharing -> no barriers in the main loop. P packed via v_cvt_pk_bf16_f32 (verified
// safe round 8). obuf overlays the dead stage region after the loop.
__global__ __launch_bounds__(512,2) void attn_kernel(const unsigned char* __restrict__ bmb,
    const unsigned short* __restrict__ WhB, const float* __restrict__ spart,
    float* __restrict__ gout, int t){
  __shared__ __align__(16) unsigned char smem[131072];   // stage[2][8][8192] -> obuf overlay
  __shared__ float ssum[2048];                           // sD0+sD1 per m (8 KB)
  __shared__ float zpart[8][32];
  int bid = blockIdx.x;
  int g = bid & 3, n0 = (bid >> 2)*32;
  int tid = threadIdx.x;
  int w = tid>>6, lane = tid&63, quad = lane>>4, l16 = lane&15;
  const float* sS0 = spart + (size_t)(0 + g)*2048;
  const float* sD0 = spart + (size_t)(4 + g)*2048;
  const float* sS1 = spart + (size_t)(8 + g)*2048;
  const float* sD1 = spart + (size_t)(12 + g)*2048;
  const unsigned short* wb = WhB + (size_t)g*262144;
  const unsigned short* wbw = wb + (size_t)(w*8)*512;    // wave's m-slice base

  // ---- issue stage group 0 (8 async 1KB chunks, direct to LDS) ----
  {
    unsigned char* lp0 = smem + (size_t)w*8192;
    #pragma unroll
    for (int o16=0;o16<8;++o16)
      __builtin_amdgcn_global_load_lds((const void*)(wbw + (size_t)o16*32768 + lane*8),
                                       (void*)(lp0 + o16*1024), 16, 0, 0);
  }
  // ---- ssum precompute (self-wave region: tid*4 in [w*256, w*256+256)) ----
  {
    float4 d0 = *(const float4*)(sD0 + tid*4);
    float4 d1 = *(const float4*)(sD1 + tid*4);
    *(float4*)&ssum[tid*4] = (float4){d0.x+d1.x, d0.y+d1.y, d0.z+d1.z, d0.w+d1.w};
  }
  float srcv0 = sS0[n0 + l16]      + sS1[n0 + l16];
  float srcv1 = sS0[n0 + 16 + l16] + sS1[n0 + 16 + l16];
  // preload both rows' 32-byte mask strips (m in [w*256, w*256+256))
  const unsigned char* mr0 = bmb + ((size_t)t*2048 + n0 + l16)*256 + w*32;
  const unsigned char* mr1 = mr0 + 16*256;
  uint4 q0 = *(const uint4*)mr0, q1 = *(const uint4*)(mr0+16);
  uint4 r0 = *(const uint4*)mr1, r1 = *(const uint4*)(mr1+16);
  unsigned mwd0[8] = {q0.x,q0.y,q0.z,q0.w, q1.x,q1.y,q1.z,q1.w};
  unsigned mwd1[8] = {r0.x,r0.y,r0.z,r0.w, r1.x,r1.y,r1.z,r1.w};
  float z0 = 0.f, z1 = 0.f;
  floatx4 acc0[8], acc1[8];
  #pragma unroll
  for (int j=0;j<8;++j){ acc0[j] = (floatx4){0.f,0.f,0.f,0.f}; acc1[j] = acc0[j]; }

  #pragma unroll
  for (int c=0; c<8; ++c){
    const int cur = c & 1;
    if (c < 7){            // issue group c+1 into the other buffer
      unsigned char* lp = smem + (size_t)(((c+1)&1)*8 + w)*8192;
      const unsigned short* gsrc = wbw + (size_t)(c+1)*512 + lane*8;
      #pragma unroll
      for (int o16=0;o16<8;++o16)
        __builtin_amdgcn_global_load_lds((const void*)(gsrc + (size_t)o16*32768),
                                         (void*)(lp + o16*1024), 16, 0, 0);
      asm volatile("s_waitcnt vmcnt(8)" ::: "memory");   // group c landed (FIFO)
    } else {
      asm volatile("s_waitcnt vmcnt(0)" ::: "memory");
    }
    __builtin_amdgcn_sched_barrier(0);
    // softmax numerators for this 32-m slab (sv from LDS ssum; lgkmcnt-tracked)
    int mk = w*256 + c*32 + quad*8;
    float4 sa = *(const float4*)&ssum[mk];
    float4 sb = *(const float4*)&ssum[mk+4];
    float sv[8] = {sa.x,sa.y,sa.z,sa.w, sb.x,sb.y,sb.z,sb.w};
    unsigned mb0 = (mwd0[c] >> (quad*8)) & 0xffu;
    unsigned mb1 = (mwd1[c] >> (quad*8)) & 0xffu;
    float p0[8], p1[8];
    #pragma unroll
    for (int j=0;j<8;++j){
      float s0 = srcv0 + sv[j];
      s0 = fmaxf(s0, 0.2f*s0);                     // leaky_relu (bit-exact)
      p0[j] = ((mb0 >> j) & 1u) ? __expf(s0) : 0.f;
      z0 += p0[j];
      float s1 = srcv1 + sv[j];
      s1 = fmaxf(s1, 0.2f*s1);
      p1[j] = ((mb1 >> j) & 1u) ? __expf(s1) : 0.f;
      z1 += p1[j];
    }
    union { short8 v; unsigned u[4]; } A0, A1;
    #pragma unroll
    for (int j2=0;j2<4;++j2){
      A0.u[j2] = cvtpk(p0[2*j2], p0[2*j2+1]);
      A1.u[j2] = cvtpk(p1[2*j2], p1[2*j2+1]);
    }
    const unsigned char* sb_base = smem + (size_t)(cur*8 + w)*8192 + lane*16;
    #pragma unroll
    for (int o16=0; o16<8; ++o16){
      short8 bfr = *(const short8*)(sb_base + o16*1024);
      acc0[o16] = MFMA16(A0.v, bfr, acc0[o16]);
      acc1[o16] = MFMA16(A1.v, bfr, acc1[o16]);
    }
  }
  z0 += __shfl_down(z0,32); z0 += __shfl_down(z0,16);
  z1 += __shfl_down(z1,32); z1 += __shfl_down(z1,16);
  if (lane < 16){ zpart[w][l16] = z0; zpart[w][16+l16] = z1; }
  __syncthreads();                     // all waves done reading stage -> safe to overlay
  float (*obuf)[32][132] = (float (*)[32][132])smem;   // 67.6 KB overlay
  if (w < 4){
    #pragma unroll
    for (int o16=0;o16<8;++o16)
      #pragma unroll
      for (int r=0;r<4;++r){
        obuf[w][quad*4+r][o16*16+l16]      = acc0[o16][r];
        obuf[w][16+quad*4+r][o16*16+l16]   = acc1[o16][r];
      }
  }
  __syncthreads();
  if (w >= 4){
    #pragma unroll
    for (int o16=0;o16<8;++o16)
      #pragma unroll
      for (int r=0;r<4;++r){
        obuf[w-4][quad*4+r][o16*16+l16]    += acc0[o16][r];
        obuf[w-4][16+quad*4+r][o16*16+l16] += acc1[o16][r];
      }
  }
  __syncthreads();
  { // normalize + elu + store: 8 floats/thread
    int row = tid>>4, c0 = (tid&15)*8;
    float z = zpart[0][row]+zpart[1][row]+zpart[2][row]+zpart[3][row]
            + zpart[4][row]+zpart[5][row]+zpart[6][row]+zpart[7][row];
    float inv = 1.f / z;
    float* go = gout + (size_t)g*262144 + (size_t)(n0+row)*128 + c0;
    #pragma unroll
    for (int j=0;j<8;++j){
      float v = (obuf[0][row][c0+j] + obuf[1][row][c0+j]
               + obuf[2][row][c0+j] + obuf[3][row][c0+j]) * inv;
      go[j] = v > 0.f ? v : __expf(v) - 1.f;       // elu
    }
  }
}

// ---- final gate + y3 + all 3 temporal conv layers; 4 rows/block, 512 blocks ----
__global__ __launch_bounds__(256) void convgate_kernel(const float* __restrict__ gbuf,
    const float* __restrict__ cell, const float* __restrict__ W, const float* __restrict__ bvec,
    const float* __restrict__ y, const float* __restrict__ cwT, const float* __restrict__ cb,
    float* __restrict__ out){
  __shared__ float hl[4][128];
  __shared__ float ylds[4][128][4];
  int tid = threadIdx.x;
  int r = tid >> 6, oc = (tid & 63)*2;
  int n = blockIdx.x*4 + r;
  size_t idx = (size_t)n*128 + oc;
  { // gate_3
    float2 g0 = *(const float2*)(gbuf+idx),        g1 = *(const float2*)(gbuf+262144+idx);
    float2 g2 = *(const float2*)(gbuf+524288+idx), g3 = *(const float2*)(gbuf+786432+idx);
    float2 cv = *(const float2*)(cell+idx);
    float fg[2]={g0.x,g0.y}, ig[2]={g1.x,g1.y}, ic[2]={g2.x,g2.y}, og[2]={g3.x,g3.y};
    float cc[2]={cv.x,cv.y};
    #pragma unroll
    for (int j=0;j<2;++j){
      float cl = cc[j]*sigm(fg[j]) + sigm(ig[j])*tanh_fast(ic[j]);
      hl[r][oc+j] = tanh_fast(cl)*sigm(og[j]);
    }
  }
  {
    float2 y0 = *(const float2*)(y+idx), y1 = *(const float2*)(y+262144+idx),
           y2 = *(const float2*)(y+524288+idx);
    float a0[2]={y0.x,y0.y}, a1[2]={y1.x,y1.y}, a2[2]={y2.x,y2.y};
    #pragma unroll
    for (int j=0;j<2;++j){
      ylds[r][oc+j][0]=a0[j]; ylds[r][oc+j][1]=a1[j]; ylds[r][oc+j][2]=a2[j];
    }
  }
  __syncthreads();
  { // y3 outproj
    float2 bb = *(const float2*)(bvec+oc);
    float acc[2] = {bb.x, bb.y};
    const float* hr = hl[r];
    for (int k=0;k<128;++k){
      float hv = hr[k];
      float2 wv = *(const float2*)(W + (size_t)k*128 + oc);
      acc[0]+=hv*wv.x; acc[1]+=hv*wv.y;
    }
    #pragma unroll
    for (int j=0;j<2;++j) ylds[r][oc+j][3] = sigm(acc[j]);
  }
  __syncthreads();
  { // layer 0: 4 -> 3
    float a0[2]={0,0}, a1[2]={0,0}, a2[2]={0,0};
    for (int k=0;k<128;++k){
      float2 w0 = *(const float2*)(cwT + k*256 + oc);
      float2 w1 = *(const float2*)(cwT + k*256 + 128 + oc);
      float4 yv = *(const float4*)&ylds[r][k][0];
      float wa[2]={w0.x,w0.y}, wb2[2]={w1.x,w1.y};
      #pragma unroll
      for (int j=0;j<2;++j){
        a0[j] += yv.x*wa[j] + yv.y*wb2[j];
        a1[j] += yv.y*wa[j] + yv.z*wb2[j];
        a2[j] += yv.z*wa[j] + yv.w*wb2[j];
      }
    }
    float2 bb = *(const float2*)(cb+oc);
    float bbv[2]={bb.x,bb.y};
    __syncthreads();
    #pragma unroll
    for (int j=0;j<2;++j){
      ylds[r][oc+j][0]=a0[j]+bbv[j]; ylds[r][oc+j][1]=a1[j]+bbv[j]; ylds[r][oc+j][2]=a2[j]+bbv[j];
    }
    __syncthreads();
  }
  { // layer 1: 3 -> 2
    float a0[2]={0,0}, a1[2]={0,0};
    for (int k=0;k<128;++k){
      float2 w0 = *(const float2*)(cwT + 32768 + k*256 + oc);
      float2 w1 = *(const float2*)(cwT + 32768 + k*256 + 128 + oc);
      float4 yv = *(const float4*)&ylds[r][k][0];
      float wa[2]={w0.x,w0.y}, wb2[2]={w1.x,w1.y};
      #pragma unroll
      for (int j=0;j<2;++j){
        a0[j] += yv.x*wa[j] + yv.y*wb2[j];
        a1[j] += yv.y*wa[j] + yv.z*wb2[j];
      }
    }
    float2 bb = *(const float2*)(cb+128+oc);
    float bbv[2]={bb.x,bb.y};
    __syncthreads();
    #pragma unroll
    for (int j=0;j<2;++j){
      ylds[r][oc+j][0]=a0[j]+bbv[j]; ylds[r][oc+j][1]=a1[j]+bbv[j];
    }
    __syncthreads();
  }
  { // layer 2: 2 -> 1
    float a0[2]={0,0};
    for (int k=0;k<128;++k){
      float2 w0 = *(const float2*)(cwT + 65536 + k*256 + oc);
      float2 w1 = *(const float2*)(cwT + 65536 + k*256 + 128 + oc);
      float4 yv = *(const float4*)&ylds[r][k][0];
      a0[0] += yv.x*w0.x + yv.y*w1.x;
      a0[1] += yv.x*w0.y + yv.y*w1.y;
    }
    float2 bb = *(const float2*)(cb+256+oc);
    float2 res = {a0[0]+bb.x, a0[1]+bb.y};
    *(float2*)(out+idx) = res;
  }
}

extern "C" void kernel_launch(void* const* d_in, const int* in_sizes, int n_in,
                              void* d_out, int out_size, void* d_ws, size_t ws_size,
                              hipStream_t stream) {
  const float* actors = (const float*)d_in[0];
  const int*   adj    = (const int*)d_in[1];
  const float* Wg     = (const float*)d_in[2];
  const float* ag     = (const float*)d_in[3];
  const float* W      = (const float*)d_in[4];
  const float* b      = (const float*)d_in[5];
  const float* h0     = (const float*)d_in[6];
  const float* cw     = (const float*)d_in[7];
  const float* cb     = (const float*)d_in[8];
  float* out = (float*)d_out;

  char* ws = (char*)d_ws;
  unsigned long long* bm = (unsigned long long*)ws;                  // 2 MB
  float* cell          = (float*)(ws + (size_t)(2u<<20));            // 1 MB
  unsigned short* WgA  = (unsigned short*)(ws + (size_t)(3u<<20));   // 256 KB bf16 swizzled
  float* cwT           = (float*)(ws + (size_t)3407872);             // 384 KB
  unsigned short* WoA  = (unsigned short*)(ws + (size_t)3801088);    // 32 KB bf16 swizzled
  float* spart         = (float*)(ws + (size_t)3932160);             // 128 KB [16][2048]
  unsigned short* WhB  = (unsigned short*)(ws + (size_t)(4u<<20));   // 2 MB bf16 swizzled
  float* gbuf          = (float*)(ws + (size_t)(7u<<20));            // 4 MB [g][n][o]
  float* yplanes       = (float*)(ws + (size_t)(11u<<20));           // 3 MB [t][n][o]

  const int XI[4] = {4, 9, 14, 19};

  prep_kernel<<<3840, 256, 0, stream>>>(actors, Wg, W, cw, adj, cell, WgA, WoA, cwT, bm);
  for (int t=0; t<4; ++t){
    gatewh_kernel<<<256, 512, 0, stream>>>(actors, gbuf, cell, h0, b, WgA, WoA, ag,
                                           yplanes, WhB, spart, XI[t]*128, t);
    attn_kernel<<<256, 512, 0, stream>>>((const unsigned char*)bm, WhB,
                                         spart, gbuf, t);
  }
  convgate_kernel<<<512, 256, 0, stream>>>(gbuf, cell, W, b, yplanes, cwT, cb, out);
}